// Round 7
// baseline (126.309 us; speedup 1.0000x reference)
//
#include <hip/hip_runtime.h>
#include <hip/hip_bf16.h>
#include <stdint.h>

typedef unsigned long long u64;
typedef unsigned int u32;

#define R_N 1000
#define K_N 80
#define NCOL 81           // K_N + 1 (background col)
#define TOPK_N 100
#define OUT_W 87          // 4 box + 1 score + 1 cls + 81 full scores
#define IMG_W_ 1333.0f
#define IMG_H_ 800.0f
#define CSTR 100          // per-class cand slots (first 100 kept per class provably suffice)
#define NQUAD ((R_N * NCOL) / 4)
#define NMAX 448          // fast-path NMS cap
#define WMAX 7
#define KM (K_N * CSTR)   // 8000 fixed candidate slots
#define SURV_CAP 2048
#define POISON 0xAAAAAAAAu  // harness re-poisons d_ws to 0xAA bytes before every launch

// ---- runtime input-dtype detection (round 2 proved f32; keep the shield) ----
__device__ __forceinline__ bool detect_f32(const void* scores) {
    const u64* p = (const u64*)scores;
    u64 acc = 0;
#pragma unroll
    for (int i = 0; i < 32; ++i) acc |= p[i];
    return (acc & 0x8000800080008000ull) != 0ull;
}
__device__ __forceinline__ float ldv(const void* b, int i, bool f32m) {
    if (f32m) return ((const float*)b)[i];
    return __uint_as_float((u32)(((const unsigned short*)b)[i]) << 16);
}
__device__ __forceinline__ void stv(void* o, int i, float v, bool f32m) {
    if (f32m) ((float*)o)[i] = v;
    else ((__hip_bfloat16*)o)[i] = __float2bfloat16(v);
}
__device__ __forceinline__ float4 ld4(const void* b, int i, bool f32m) {  // i % 4 == 0
    if (f32m) return ((const float4*)b)[i >> 2];
    ushort4 u = ((const ushort4*)b)[i >> 2];
    float4 f;
    f.x = __uint_as_float((u32)u.x << 16); f.y = __uint_as_float((u32)u.y << 16);
    f.z = __uint_as_float((u32)u.z << 16); f.w = __uint_as_float((u32)u.w << 16);
    return f;
}
__device__ __forceinline__ u32 f32_order(float f) {
    u32 u = __float_as_uint(f);
    return u ^ (((u32)((int)u >> 31)) | 0x80000000u);
}
__device__ __forceinline__ float f32_unorder(u32 o) {
    u32 u = (o & 0x80000000u) ? (o ^ 0x80000000u) : ~o;
    return __uint_as_float(u);
}
// bucket on high bits of the score-order field (keys: osc<<27 | inv_flat<<10 | prop)
__device__ __forceinline__ int bucket_of(u64 k) {
    int b = (int)(k >> 43) - 0xBD00;
    return b < 0 ? 0 : (b > 1023 ? 1023 : b);
}

// software grid barrier, SELF-CLEANING (no memset node needed):
// counter starts at POISON (0xAA re-poison) or 0; first arrival CASes POISON->0,
// then every block adds 1 and spins until count >= nblk. All 80 blocks are
// co-resident (1 block/CU via LDS, 80 <= 256 CUs); device-scope atomics cross XCDs.
__device__ __forceinline__ void grid_barrier(u32* bar, u32 nblk) {
    __syncthreads();
    if (threadIdx.x == 0) {
        __threadfence();   // release all prior global writes
        atomicCAS(bar, POISON, 0u);   // exactly one success; post-clean values stay in [0, nblk]
        __hip_atomic_fetch_add(bar, 1u, __ATOMIC_ACQ_REL, __HIP_MEMORY_SCOPE_AGENT);
        while (__hip_atomic_load(bar, __ATOMIC_ACQUIRE, __HIP_MEMORY_SCOPE_AGENT) < nblk) {
            __builtin_amdgcn_s_sleep(2);
        }
    }
    __syncthreads();
}

struct P2 {                       // per-class NMS scratch (phase 2)
    float4 bx4[R_N];
    u64 key_s[R_N];
    u64 pool[NMAX * WMAX];        // ukey pre-sort / Mrow bitmatrix / keep[] fallback
    float area[R_N];
    float sc[R_N];
    u64 keep_words[16];
    int s_n;
};
struct P3 {                       // global top-100 scratch (phase 3, block 0)
    u64 keys[KM];
    u64 surv[SURV_CAP];
    u32 hist[1024];
    u32 scan[256];
    int meta[4];                  // [0]=surv count, [1]=bucket cutoff B
};
union SMEM { P2 p2; P3 p3; };

__device__ __forceinline__ void write_row(void* outp, const void* boxes, const void* scores,
                                          u64 x, int rank, bool f32m) {
    int prop = (int)(x & 0x3FFull);
    int flat = 131071 - (int)((x >> 10) & 0x1FFFFull);
    int cls = flat / R_N;
    float score = f32_unorder((u32)((x >> 27) & 0xFFFFFFFFull));
    int ob = rank * OUT_W;
    float4 bx = ld4(boxes, prop * (K_N * 4) + cls * 4, f32m);
    stv(outp, ob + 0, fminf(fmaxf(bx.x, 0.f), IMG_W_), f32m);
    stv(outp, ob + 1, fminf(fmaxf(bx.y, 0.f), IMG_H_), f32m);
    stv(outp, ob + 2, fminf(fmaxf(bx.z, 0.f), IMG_W_), f32m);
    stv(outp, ob + 3, fminf(fmaxf(bx.w, 0.f), IMG_H_), f32m);
    stv(outp, ob + 4, score, f32m);
    stv(outp, ob + 5, (float)cls, f32m);
    const int sb = prop * NCOL;
#pragma unroll 9
    for (int j = 0; j < NCOL; ++j)
        stv(outp, ob + 6 + j, ldv(scores, sb + j, f32m), f32m);
}

__global__ __launch_bounds__(256, 1) void k_all(const void* __restrict__ boxes,
                                                const void* __restrict__ scores,
                                                float* __restrict__ hdr,
                                                u32* __restrict__ bars,
                                                u64* __restrict__ cand,
                                                void* __restrict__ outp) {
    __shared__ SMEM sm;
    __shared__ float s_sum[4], s_max[4];
    __shared__ float s_thres;

    const int bid = blockIdx.x, tid = threadIdx.x;
    const int lane = tid & 63, wv = tid >> 6;
    const bool f32m = detect_f32(scores);
    const int c = bid;

    // ================= phase 1: stage score column (overlap) + stat partials + zero d_out ====
    {
        // issue phase-2 column staging first so its scattered-load latency overlaps phase 1
        for (int r = tid; r < R_N; r += 256) sm.p2.sc[r] = ldv(scores, r * NCOL + c, f32m);

        const int zn = f32m ? (TOPK_N * OUT_W) : (TOPK_N * OUT_W / 2);
        for (int t = bid * 256 + tid; t < zn; t += K_N * 256) ((int*)outp)[t] = 0;

        float sum = 0.f, mx = -1e30f;
        int q = bid * 256 + tid;
        if (q < NQUAD) {
            float4 v = ld4(scores, q * 4, f32m);
            int m = (q * 4) % NCOL;
            float vv[4] = {v.x, v.y, v.z, v.w};
#pragma unroll
            for (int e = 0; e < 4; ++e) {
                int mm = m + e; if (mm >= NCOL) mm -= NCOL;
                if (mm != K_N) { sum += vv[e]; mx = fmaxf(mx, vv[e]); }
            }
        }
#pragma unroll
        for (int off = 32; off > 0; off >>= 1) {
            sum += __shfl_down(sum, off);
            mx = fmaxf(mx, __shfl_down(mx, off));
        }
        if (lane == 0) { s_sum[wv] = sum; s_max[wv] = mx; }
        __syncthreads();
        if (tid == 0) {
            hdr[2 * bid] = s_sum[0] + s_sum[1] + s_sum[2] + s_sum[3];
            hdr[2 * bid + 1] = fmaxf(fmaxf(s_max[0], s_max[1]), fmaxf(s_max[2], s_max[3]));
        }
    }
    grid_barrier(&bars[0], K_N);

    // ================= phase 2: per-class NMS (block = class) ==============
    {
        // wave-parallel threshold reduction (80 partials; lane + lane+64)
        if (wv == 0) {
            float S = hdr[2 * lane], M = hdr[2 * lane + 1];
            if (lane + 64 < K_N) {
                S += hdr[2 * (lane + 64)];
                M = fmaxf(M, hdr[2 * (lane + 64) + 1]);
            }
#pragma unroll
            for (int off = 32; off > 0; off >>= 1) {
                S += __shfl_down(S, off);
                M = fmaxf(M, __shfl_down(M, off));
            }
            if (lane == 0)
                s_thres = fminf(0.05f, 0.5f * (S / (float)(R_N * K_N) + M));
        }
        __syncthreads();
        const float thres = s_thres;

        // wave-0: ballot stream-compaction of keys (no barriers inside)
        u64* ukey = sm.p2.pool;
        const u64 below = (lane == 0) ? 0ull : (~0ull >> (64 - lane));
        if (wv == 0) {
            int nn = 0;
            for (int r0 = 0; r0 < R_N; r0 += 64) {
                int r = r0 + lane;
                bool pred = (r < R_N) && (sm.p2.sc[r] > thres);
                u64 m = __ballot(pred);
                if (pred) {
                    int slot = nn + __popcll(m & below);
                    ukey[slot] = ((u64)f32_order(sm.p2.sc[r]) << 32) | (u64)(u32)(R_N - 1 - r);
                }
                nn += __popcll(m);
            }
            if (lane == 0) sm.p2.s_n = nn;
        }
        __syncthreads();
        const int n = sm.p2.s_n;

        // counting-rank sort + box gather (all 256 threads)
        for (int j = tid; j < n; j += 256) {
            u64 kj = ukey[j];
            int rank = 0;
            for (int k = 0; k < n; ++k) rank += (ukey[k] > kj) ? 1 : 0;
            int r = (R_N - 1) - (int)(kj & 0xFFFFFFFFull);
            float4 b = ld4(boxes, r * (K_N * 4) + c * 4, f32m);
            float x1 = fminf(fmaxf(b.x, 0.f), IMG_W_);
            float y1 = fminf(fmaxf(b.y, 0.f), IMG_H_);
            float x2 = fminf(fmaxf(b.z, 0.f), IMG_W_);
            float y2 = fminf(fmaxf(b.w, 0.f), IMG_H_);
            sm.p2.key_s[rank] = kj;
            sm.p2.bx4[rank] = make_float4(x1, y1, x2, y2);
            sm.p2.area[rank] = fmaxf(x2 - x1, 0.f) * fmaxf(y2 - y1, 0.f);
        }
        __syncthreads();

        if (n <= NMAX) {
            // suppression bit-matrix, built by all 4 waves (w strided by wave)
            const int W = (n + 63) >> 6;
            u64* Mrow = sm.p2.pool;            // ukey dead after sort
            for (int w = wv; w < W; w += 4) {
                int j = w * 64 + lane;
                bool jv = j < n;
                float4 bj = jv ? sm.p2.bx4[j] : make_float4(0.f, 0.f, 0.f, 0.f);
                float aj = jv ? sm.p2.area[j] : 0.f;
                for (int i = 0; i < n; ++i) {
                    float4 bi = sm.p2.bx4[i];
                    float ai = sm.p2.area[i];
                    float xx1 = fmaxf(bi.x, bj.x), yy1 = fmaxf(bi.y, bj.y);
                    float xx2 = fminf(bi.z, bj.z), yy2 = fminf(bi.w, bj.w);
                    float inter = fmaxf(xx2 - xx1, 0.f) * fmaxf(yy2 - yy1, 0.f);
                    bool sup = jv && (j > i) &&
                               (inter / fmaxf(ai + aj - inter, 1e-9f) > 0.5f);
                    u64 m = __ballot(sup);
                    if (lane == 0) Mrow[i * W + w] = m;
                }
            }
            __syncthreads();

            // wave-0: register keep-propagation with depth-8 LDS prefetch (no barriers)
            if (wv == 0) {
                u64 keep_w = 0;
                if (lane < W) {
                    int rem = n - lane * 64;
                    keep_w = (rem >= 64) ? ~0ull : ((1ull << rem) - 1ull);
                }
                const int lw = (lane < W) ? lane : 0;
                u64 fifo[8];
#pragma unroll
                for (int d = 0; d < 8; ++d) fifo[d] = (d < n) ? Mrow[d * W + lw] : 0ull;
                for (int ib = 0; ib < n; ib += 8) {
#pragma unroll
                    for (int d = 0; d < 8; ++d) {
                        int i = ib + d;
                        if (i >= n) break;
                        u64 row = fifo[d];
                        int ip = i + 8;
                        fifo[d] = (ip < n) ? Mrow[ip * W + lw] : 0ull;
                        u64 kw = __shfl(keep_w, i >> 6);
                        if ((kw >> (i & 63)) & 1ull) keep_w &= ~row;
                    }
                }
                if (lane < W) sm.p2.keep_words[lane] = keep_w;
                if (lane >= W && lane < 16) sm.p2.keep_words[lane] = 0;
            }
        } else {
            // fallback: block-wide serial greedy (block-uniform barriers)
            int* keep = (int*)sm.p2.pool;
            for (int j = tid; j < n; j += 256) keep[j] = 1;
            __syncthreads();
            for (int i = 0; i < n - 1; ++i) {
                __syncthreads();
                if (!keep[i]) continue;
                float4 bi = sm.p2.bx4[i];
                float ai = sm.p2.area[i];
                for (int j = i + 1 + tid; j < n; j += 256) {
                    if (!keep[j]) continue;
                    float xx1 = fmaxf(bi.x, sm.p2.bx4[j].x), yy1 = fmaxf(bi.y, sm.p2.bx4[j].y);
                    float xx2 = fminf(bi.z, sm.p2.bx4[j].z), yy2 = fminf(bi.w, sm.p2.bx4[j].w);
                    float inter = fmaxf(xx2 - xx1, 0.f) * fmaxf(yy2 - yy1, 0.f);
                    if (inter / fmaxf(ai + sm.p2.area[j] - inter, 1e-9f) > 0.5f) keep[j] = 0;
                }
            }
            __syncthreads();
            if (wv == 0) {
                for (int w = 0; w < 16; ++w) {
                    int j = w * 64 + lane;
                    u64 m = __ballot((j < n) && keep[j]);
                    if (lane == 0) sm.p2.keep_words[w] = m;
                }
            }
        }
        __syncthreads();

        // wave-0: emit first <=100 kept per class, zero-pad remaining slots
        if (wv == 0) {
            int kb = 0;
            for (int j0 = 0; j0 < n; j0 += 64) {
                int j = j0 + lane;
                u64 mw = sm.p2.keep_words[j0 >> 6];
                bool kp = (j < n) && ((mw >> lane) & 1ull);
                u64 mm = __ballot(kp);
                int kr = kb + __popcll(mm & below);
                if (kp && kr < CSTR) {
                    u64 kj = sm.p2.key_s[j];
                    u32 osc = (u32)(kj >> 32);
                    int rr = (R_N - 1) - (int)(kj & 0xFFFFFFFFull);
                    int flat = c * R_N + j;
                    cand[c * CSTR + kr] =
                        ((u64)osc << 27) | ((u64)(u32)(131071 - flat) << 10) | (u64)(u32)rr;
                }
                kb += __popcll(mm);
            }
            if (kb > CSTR) kb = CSTR;
            for (int k2 = kb + lane; k2 < CSTR; k2 += 64) cand[c * CSTR + k2] = 0;
        }
    }
    grid_barrier(&bars[1], K_N);

    // ================= phase 3: block 0 — global top-100 + output ==========
    if (bid == 0) {
        for (int t = tid; t < KM; t += 256) sm.p3.keys[t] = cand[t];
        for (int t = tid; t < 1024; t += 256) sm.p3.hist[t] = 0;
        if (tid == 0) { sm.p3.meta[0] = 0; sm.p3.meta[1] = 1024; }
        __syncthreads();

        for (int t = tid; t < KM; t += 256) {
            u64 k = sm.p3.keys[t];
            if (k) atomicAdd(&sm.p3.hist[bucket_of(k)], 1u);
        }
        __syncthreads();

        // suffix sums over 1024 buckets (4 per thread + block suffix-scan)
        u32 h[4];
#pragma unroll
        for (int i = 0; i < 4; ++i) h[i] = sm.p3.hist[4 * tid + i];
        sm.p3.scan[tid] = h[0] + h[1] + h[2] + h[3];
        __syncthreads();
        for (int off = 1; off < 256; off <<= 1) {
            u32 v = sm.p3.scan[tid] + ((tid + off < 256) ? sm.p3.scan[tid + off] : 0u);
            __syncthreads();
            sm.p3.scan[tid] = v;
            __syncthreads();
        }
        u32 total = sm.p3.scan[0];
        u32 carry = (tid < 255) ? sm.p3.scan[tid + 1] : 0u;
        u32 sfx[4];
        sfx[3] = carry + h[3];
        sfx[2] = sfx[3] + h[2];
        sfx[1] = sfx[2] + h[1];
        sfx[0] = sfx[1] + h[0];
#pragma unroll
        for (int i = 0; i < 4; ++i) sm.p3.hist[4 * tid + i] = sfx[i];
        __syncthreads();

        u32 target = total < (u32)TOPK_N ? total : (u32)TOPK_N;
        if (target > 0) {
#pragma unroll
            for (int i = 0; i < 4; ++i) {
                int b = 4 * tid + i;
                u32 sb = sm.p3.hist[b];
                u32 snext = (b < 1023) ? sm.p3.hist[b + 1] : 0u;
                if (sb >= target && snext < target) sm.p3.meta[1] = b;  // unique writer
            }
        }
        __syncthreads();
        const int B = sm.p3.meta[1];

        // compact survivors (bucket >= B); order-free, exact ranks computed below
        for (int t = tid; t < KM; t += 256) {
            u64 k = sm.p3.keys[t];
            if (k && bucket_of(k) >= B) {
                int idx = atomicAdd(&sm.p3.meta[0], 1);
                if (idx < SURV_CAP) sm.p3.surv[idx] = k;
            }
        }
        __syncthreads();
        const int Sn = sm.p3.meta[0];

        if (Sn <= SURV_CAP) {
            for (int s = tid; s < Sn; s += 256) {
                u64 x = sm.p3.surv[s];
                int rank = 0;
                for (int i = 0; i < Sn; ++i) rank += (sm.p3.surv[i] > x) ? 1 : 0;
                if (rank < TOPK_N) write_row(outp, boxes, scores, x, rank, f32m);
            }
        } else {
            // pathological fallback: rank survivors against all keys
            for (int t = tid; t < KM; t += 256) {
                u64 x = sm.p3.keys[t];
                if (x && bucket_of(x) >= B) {
                    int rank = 0;
                    for (int i = 0; i < KM; ++i) rank += (sm.p3.keys[i] > x) ? 1 : 0;
                    if (rank < TOPK_N) write_row(outp, boxes, scores, x, rank, f32m);
                }
            }
        }
    }
}

extern "C" void kernel_launch(void* const* d_in, const int* in_sizes, int n_in,
                              void* d_out, int out_size, void* d_ws, size_t ws_size,
                              hipStream_t stream) {
    const void* boxes = d_in[0];
    const void* scores = d_in[1];
    float* hdr = (float*)d_ws;                     // 160 f32 partials at [0, 640)
    u32* bars = (u32*)((char*)d_ws + 768);         // 2 self-cleaning barrier counters
    u64* cand = (u64*)((char*)d_ws + 1024);        // 8000 u64 candidate slots

    k_all<<<dim3(K_N), dim3(256), 0, stream>>>(boxes, scores, hdr, bars, cand, d_out);
}

// Round 8
// 121.982 us; speedup vs baseline: 1.0355x; 1.0355x over previous
//
#include <hip/hip_runtime.h>
#include <stdint.h>

typedef unsigned long long u64;
typedef unsigned int u32;

#define R_N 1000
#define K_N 80
#define NCOL 81           // K_N + 1 (background col)
#define TOPK_N 100
#define OUT_W 87          // 4 box + 1 score + 1 cls + 81 full scores
#define IMG_W_ 1333.0f
#define IMG_H_ 800.0f
#define CSTR 100          // per-class cand slots (first 100 kept per class provably suffice)
#define NQUAD ((R_N * NCOL) / 4)
#define NMAX 448          // fast-path NMS cap
#define WMAX 7
#define KM (K_N * CSTR)   // 8000 fixed candidate slots
#define SURV_CAP 2048
#define POISON 0xAAAAAAAAu  // harness re-poisons d_ws to 0xAA before every launch

__device__ __forceinline__ u32 f32_order(float f) {
    u32 u = __float_as_uint(f);
    return u ^ (((u32)((int)u >> 31)) | 0x80000000u);
}
__device__ __forceinline__ float f32_unorder(u32 o) {
    u32 u = (o & 0x80000000u) ? (o ^ 0x80000000u) : ~o;
    return __uint_as_float(u);
}
// bucket on high bits of the score-order field (keys: osc<<27 | inv_flat<<10 | prop)
__device__ __forceinline__ int bucket_of(u64 k) {
    int b = (int)(k >> 43) - 0xBD00;
    return b < 0 ? 0 : (b > 1023 ? 1023 : b);
}
// agent-scope accessors: architecturally cross-XCD visible (not just empirically)
__device__ __forceinline__ void st_a64(u64* p, u64 v) {
    __hip_atomic_store(p, v, __ATOMIC_RELAXED, __HIP_MEMORY_SCOPE_AGENT);
}
__device__ __forceinline__ u64 ld_a64(const u64* p) {
    return __hip_atomic_load(p, __ATOMIC_RELAXED, __HIP_MEMORY_SCOPE_AGENT);
}
__device__ __forceinline__ void st_a32(u32* p, u32 v) {
    __hip_atomic_store(p, v, __ATOMIC_RELAXED, __HIP_MEMORY_SCOPE_AGENT);
}
__device__ __forceinline__ u32 ld_a32(const u32* p) {
    return __hip_atomic_load(p, __ATOMIC_RELAXED, __HIP_MEMORY_SCOPE_AGENT);
}

// software grid barrier, self-cleaning. Load-first: only blocks that actually
// observe POISON issue the CAS (one succeeds); everyone else pays a plain L2
// read instead of a serialized RMW. 80 blocks co-resident (1 block/CU).
__device__ __forceinline__ void grid_barrier(u32* bar, u32 nblk) {
    __syncthreads();
    if (threadIdx.x == 0) {
        __threadfence();   // release this thread's prior global writes
        if (__hip_atomic_load(bar, __ATOMIC_RELAXED, __HIP_MEMORY_SCOPE_AGENT) == POISON)
            atomicCAS(bar, POISON, 0u);   // exactly one success; value then stays in [0, nblk]
        __hip_atomic_fetch_add(bar, 1u, __ATOMIC_ACQ_REL, __HIP_MEMORY_SCOPE_AGENT);
        while (__hip_atomic_load(bar, __ATOMIC_ACQUIRE, __HIP_MEMORY_SCOPE_AGENT) < nblk)
            __builtin_amdgcn_s_sleep(1);
    }
    __syncthreads();
}

struct P2 {                       // per-class NMS scratch
    float4 bx4[R_N];
    u64 key_s[R_N];
    u64 pool[NMAX * WMAX];        // ukey pre-sort / Mrow bitmatrix / keep[] fallback
    float area[R_N];
    float sc[R_N];                // staged score column (survives both NMS passes)
    u64 keep_words[16];
    int s_n;
};
struct P3 {                       // global top-100 scratch (block 0)
    u64 keys[KM];
    u64 surv[SURV_CAP];
    u64 sel[TOPK_N];
    u32 hist[1024];
    u32 scan[256];
    int meta[4];                  // [0]=surv count, [1]=bucket cutoff B
};
union SMEM { P2 p2; P3 p3; };

__global__ __launch_bounds__(256, 1) void k_all(const float* __restrict__ boxes,
                                                const float* __restrict__ scores,
                                                u32* __restrict__ hdrw,
                                                u32* __restrict__ bars,
                                                u64* __restrict__ cand,
                                                float* __restrict__ outp) {
    __shared__ SMEM sm;
    __shared__ float s_sum[4], s_max[4];
    __shared__ float s_thres;

    const int bid = blockIdx.x, tid = threadIdx.x;
    const int lane = tid & 63, wv = tid >> 6;
    const int c = bid;
    const u64 below = (lane == 0) ? 0ull : (~0ull >> (64 - lane));

    // ---- stage score column c (scattered; overlaps stats below) ----
    for (int r = tid; r < R_N; r += 256) sm.p2.sc[r] = scores[r * NCOL + c];

    // ---- stats partial (sum,max of fg scores over this block's quad slice) ----
    {
        float sum = 0.f, mx = -1e30f;
        int q = bid * 256 + tid;               // 80*256 = 20480 >= 20250 quads
        if (q < NQUAD) {
            float4 v = ((const float4*)scores)[q];
            int m = (q * 4) % NCOL;
            float vv[4] = {v.x, v.y, v.z, v.w};
#pragma unroll
            for (int e = 0; e < 4; ++e) {
                int mm = m + e; if (mm >= NCOL) mm -= NCOL;
                if (mm != K_N) { sum += vv[e]; mx = fmaxf(mx, vv[e]); }
            }
        }
#pragma unroll
        for (int off = 32; off > 0; off >>= 1) {
            sum += __shfl_down(sum, off);
            mx = fmaxf(mx, __shfl_down(mx, off));
        }
        if (lane == 0) { s_sum[wv] = sum; s_max[wv] = mx; }
        __syncthreads();                       // also publishes sc[] for the NMS pass
        if (tid == 0) {
            float S = s_sum[0] + s_sum[1] + s_sum[2] + s_sum[3];
            float M = fmaxf(fmaxf(s_max[0], s_max[1]), fmaxf(s_max[2], s_max[3]));
            st_a32(&hdrw[2 * bid], __float_as_uint(S));
            st_a32(&hdrw[2 * bid + 1], __float_as_uint(M));
        }
    }

    // ---- NMS: speculative pass at th=0.05 (always correct in practice), exact redo if not ----
    float th = 0.05f;
    for (int pass = 0; ; ++pass) {
        // compact valid (sc > th); key = (score desc, orig idx asc) — wave 0 only
        u64* ukey = sm.p2.pool;
        if (wv == 0) {
            int nn = 0;
            for (int r0 = 0; r0 < R_N; r0 += 64) {
                int r = r0 + lane;
                bool pred = (r < R_N) && (sm.p2.sc[r] > th);
                u64 m = __ballot(pred);
                if (pred) {
                    int slot = nn + __popcll(m & below);
                    ukey[slot] = ((u64)f32_order(sm.p2.sc[r]) << 32) | (u64)(u32)(R_N - 1 - r);
                }
                nn += __popcll(m);
            }
            if (lane == 0) sm.p2.s_n = nn;
        }
        __syncthreads();
        const int n = sm.p2.s_n;

        // counting-rank sort + clipped box gather (all 256 threads)
        for (int j = tid; j < n; j += 256) {
            u64 kj = ukey[j];
            int rank = 0;
            for (int k = 0; k < n; ++k) rank += (ukey[k] > kj) ? 1 : 0;
            int r = (R_N - 1) - (int)(kj & 0xFFFFFFFFull);
            float4 b = ((const float4*)boxes)[r * K_N + c];
            float x1 = fminf(fmaxf(b.x, 0.f), IMG_W_);
            float y1 = fminf(fmaxf(b.y, 0.f), IMG_H_);
            float x2 = fminf(fmaxf(b.z, 0.f), IMG_W_);
            float y2 = fminf(fmaxf(b.w, 0.f), IMG_H_);
            sm.p2.key_s[rank] = kj;
            sm.p2.bx4[rank] = make_float4(x1, y1, x2, y2);
            sm.p2.area[rank] = fmaxf(x2 - x1, 0.f) * fmaxf(y2 - y1, 0.f);
        }
        __syncthreads();

        if (n <= NMAX) {
            // suppression bit-matrix (throughput), then register keep-propagation (latency)
            const int W = (n + 63) >> 6;
            u64* Mrow = sm.p2.pool;            // ukey dead after sort
            for (int w = wv; w < W; w += 4) {
                int j = w * 64 + lane;
                bool jv = j < n;
                float4 bj = jv ? sm.p2.bx4[j] : make_float4(0.f, 0.f, 0.f, 0.f);
                float aj = jv ? sm.p2.area[j] : 0.f;
                for (int i = 0; i < n; ++i) {
                    float4 bi = sm.p2.bx4[i];
                    float ai = sm.p2.area[i];
                    float xx1 = fmaxf(bi.x, bj.x), yy1 = fmaxf(bi.y, bj.y);
                    float xx2 = fminf(bi.z, bj.z), yy2 = fminf(bi.w, bj.w);
                    float inter = fmaxf(xx2 - xx1, 0.f) * fmaxf(yy2 - yy1, 0.f);
                    bool sup = jv && (j > i) &&
                               (inter / fmaxf(ai + aj - inter, 1e-9f) > 0.5f);
                    u64 m = __ballot(sup);
                    if (lane == 0) Mrow[i * W + w] = m;
                }
            }
            __syncthreads();

            if (wv == 0) {
                u64 keep_w = 0;
                if (lane < W) {
                    int rem = n - lane * 64;
                    keep_w = (rem >= 64) ? ~0ull : ((1ull << rem) - 1ull);
                }
                const int lw = (lane < W) ? lane : 0;
                u64 fifo[8];
#pragma unroll
                for (int d = 0; d < 8; ++d) fifo[d] = (d < n) ? Mrow[d * W + lw] : 0ull;
                for (int ib = 0; ib < n; ib += 8) {
#pragma unroll
                    for (int d = 0; d < 8; ++d) {
                        int i = ib + d;
                        if (i >= n) break;
                        u64 row = fifo[d];
                        int ip = i + 8;
                        fifo[d] = (ip < n) ? Mrow[ip * W + lw] : 0ull;
                        u64 kw = __shfl(keep_w, i >> 6);
                        if ((kw >> (i & 63)) & 1ull) keep_w &= ~row;
                    }
                }
                if (lane < W) sm.p2.keep_words[lane] = keep_w;
                if (lane >= W && lane < 16) sm.p2.keep_words[lane] = 0;
            }
        } else {
            // fallback: block-wide serial greedy (cold; correctness only)
            int* keep = (int*)sm.p2.pool;
            for (int j = tid; j < n; j += 256) keep[j] = 1;
            __syncthreads();
            for (int i = 0; i < n - 1; ++i) {
                __syncthreads();
                if (!keep[i]) continue;
                float4 bi = sm.p2.bx4[i];
                float ai = sm.p2.area[i];
                for (int j = i + 1 + tid; j < n; j += 256) {
                    if (!keep[j]) continue;
                    float xx1 = fmaxf(bi.x, sm.p2.bx4[j].x), yy1 = fmaxf(bi.y, sm.p2.bx4[j].y);
                    float xx2 = fminf(bi.z, sm.p2.bx4[j].z), yy2 = fminf(bi.w, sm.p2.bx4[j].w);
                    float inter = fmaxf(xx2 - xx1, 0.f) * fmaxf(yy2 - yy1, 0.f);
                    if (inter / fmaxf(ai + sm.p2.area[j] - inter, 1e-9f) > 0.5f) keep[j] = 0;
                }
            }
            __syncthreads();
            if (wv == 0) {
                for (int w = 0; w < 16; ++w) {
                    int j = w * 64 + lane;
                    u64 m = __ballot((j < n) && keep[j]);
                    if (lane == 0) sm.p2.keep_words[w] = m;
                }
            }
        }
        __syncthreads();

        // emit first <=100 kept per class, zero-pad remaining slots (agent-scope stores)
        if (wv == 0) {
            int kb = 0;
            for (int j0 = 0; j0 < n; j0 += 64) {
                int j = j0 + lane;
                u64 mw = sm.p2.keep_words[j0 >> 6];
                bool kp = (j < n) && ((mw >> lane) & 1ull);
                u64 mm = __ballot(kp);
                int kr = kb + __popcll(mm & below);
                if (kp && kr < CSTR) {
                    u64 kj = sm.p2.key_s[j];
                    u32 osc = (u32)(kj >> 32);
                    int rr = (R_N - 1) - (int)(kj & 0xFFFFFFFFull);
                    int flat = c * R_N + j;
                    st_a64(&cand[c * CSTR + kr],
                           ((u64)osc << 27) | ((u64)(u32)(131071 - flat) << 10) | (u64)(u32)rr);
                }
                kb += __popcll(mm);
            }
            if (kb > CSTR) kb = CSTR;
            for (int k2 = kb + lane; k2 < CSTR; k2 += 64) st_a64(&cand[c * CSTR + k2], 0ull);
        }

        if (pass == 0) {
            grid_barrier(&bars[0], K_N);
            // exact threshold from all 80 partials (wave-parallel, identical in every block)
            if (wv == 0) {
                float S = __uint_as_float(ld_a32(&hdrw[2 * lane]));
                float M = __uint_as_float(ld_a32(&hdrw[2 * lane + 1]));
                if (lane + 64 < K_N) {
                    S += __uint_as_float(ld_a32(&hdrw[2 * (lane + 64)]));
                    M = fmaxf(M, __uint_as_float(ld_a32(&hdrw[2 * (lane + 64) + 1])));
                }
#pragma unroll
                for (int off = 32; off > 0; off >>= 1) {
                    S += __shfl_down(S, off);
                    M = fmaxf(M, __shfl_down(M, off));
                }
                if (lane == 0)
                    s_thres = fminf(0.05f, 0.5f * (S / (float)(R_N * K_N) + M));
            }
            __syncthreads();
            if (s_thres == 0.05f) break;       // hot path: speculation was exact
            th = s_thres;                      // cold: redo with the true threshold
        } else {
            grid_barrier(&bars[1], K_N);
            break;
        }
    }

    // ---- phase 3: block 0 — global top-100 via bucket cutoff + exact ranks + output ----
    if (bid == 0) {
        for (int t = tid; t < KM; t += 256) sm.p3.keys[t] = ld_a64(&cand[t]);
        for (int t = tid; t < 1024; t += 256) sm.p3.hist[t] = 0;
        if (tid < TOPK_N) sm.p3.sel[tid] = 0;
        if (tid == 0) { sm.p3.meta[0] = 0; sm.p3.meta[1] = 1024; }
        __syncthreads();

        for (int t = tid; t < KM; t += 256) {
            u64 k = sm.p3.keys[t];
            if (k) atomicAdd(&sm.p3.hist[bucket_of(k)], 1u);
        }
        __syncthreads();

        // suffix sums over 1024 buckets (4/thread + block suffix-scan)
        u32 h[4];
#pragma unroll
        for (int i = 0; i < 4; ++i) h[i] = sm.p3.hist[4 * tid + i];
        sm.p3.scan[tid] = h[0] + h[1] + h[2] + h[3];
        __syncthreads();
        for (int off = 1; off < 256; off <<= 1) {
            u32 v = sm.p3.scan[tid] + ((tid + off < 256) ? sm.p3.scan[tid + off] : 0u);
            __syncthreads();
            sm.p3.scan[tid] = v;
            __syncthreads();
        }
        u32 total = sm.p3.scan[0];
        u32 carry = (tid < 255) ? sm.p3.scan[tid + 1] : 0u;
        u32 sfx[4];
        sfx[3] = carry + h[3];
        sfx[2] = sfx[3] + h[2];
        sfx[1] = sfx[2] + h[1];
        sfx[0] = sfx[1] + h[0];
#pragma unroll
        for (int i = 0; i < 4; ++i) sm.p3.hist[4 * tid + i] = sfx[i];
        __syncthreads();

        u32 target = total < (u32)TOPK_N ? total : (u32)TOPK_N;
        if (target > 0) {
#pragma unroll
            for (int i = 0; i < 4; ++i) {
                int b = 4 * tid + i;
                u32 sb = sm.p3.hist[b];
                u32 snext = (b < 1023) ? sm.p3.hist[b + 1] : 0u;
                if (sb >= target && snext < target) sm.p3.meta[1] = b;  // unique writer
            }
        }
        __syncthreads();
        const int B = sm.p3.meta[1];

        // compact survivors (bucket >= B); their survivor-rank == global rank
        for (int t = tid; t < KM; t += 256) {
            u64 k = sm.p3.keys[t];
            if (k && bucket_of(k) >= B) {
                int idx = atomicAdd(&sm.p3.meta[0], 1);
                if (idx < SURV_CAP) sm.p3.surv[idx] = k;
            }
        }
        __syncthreads();
        const int Sn = sm.p3.meta[0];

        if (Sn <= SURV_CAP) {
            for (int s = tid; s < Sn; s += 256) {
                u64 x = sm.p3.surv[s];
                int rank = 0;
                for (int i = 0; i < Sn; ++i) rank += (sm.p3.surv[i] > x) ? 1 : 0;
                if (rank < (int)target) sm.p3.sel[rank] = x;
            }
        } else {
            // pathological fallback: rank candidate against all keys
            for (int t = tid; t < KM; t += 256) {
                u64 x = sm.p3.keys[t];
                if (x && bucket_of(x) >= B) {
                    int rank = 0;
                    for (int i = 0; i < KM; ++i) rank += (sm.p3.keys[i] > x) ? 1 : 0;
                    if (rank < (int)target) sm.p3.sel[rank] = x;
                }
            }
        }
        __syncthreads();

        // cooperative coalesced epilogue: all 8700 outputs (zero rows included)
        for (int e = tid; e < TOPK_N * OUT_W; e += 256) {
            int row = e / OUT_W, col = e - row * OUT_W;
            u64 key = sm.p3.sel[row];
            float val = 0.f;
            if (key != 0ull) {
                int prop = (int)(key & 0x3FFull);
                int flat = 131071 - (int)((key >> 10) & 0x1FFFFull);
                int cls = flat / R_N;
                if (col < 4) {
                    float b = boxes[prop * (K_N * 4) + cls * 4 + col];
                    float lim = (col & 1) ? IMG_H_ : IMG_W_;
                    val = fminf(fmaxf(b, 0.f), lim);
                } else if (col == 4) {
                    val = f32_unorder((u32)((key >> 27) & 0xFFFFFFFFull));
                } else if (col == 5) {
                    val = (float)cls;
                } else {
                    val = scores[prop * NCOL + (col - 6)];
                }
            }
            outp[e] = val;
        }
    }
}

extern "C" void kernel_launch(void* const* d_in, const int* in_sizes, int n_in,
                              void* d_out, int out_size, void* d_ws, size_t ws_size,
                              hipStream_t stream) {
    const float* boxes = (const float*)d_in[0];
    const float* scores = (const float*)d_in[1];
    u32* hdrw = (u32*)d_ws;                        // 160 u32 partials at [0, 640)
    u32* bars = (u32*)((char*)d_ws + 768);         // 2 self-cleaning barrier counters
    u64* cand = (u64*)((char*)d_ws + 1024);        // 8000 u64 candidate slots

    k_all<<<dim3(K_N), dim3(256), 0, stream>>>(boxes, scores, hdrw, bars, cand, (float*)d_out);
}

// Round 9
// 111.373 us; speedup vs baseline: 1.1341x; 1.0953x over previous
//
#include <hip/hip_runtime.h>
#include <stdint.h>

typedef unsigned long long u64;
typedef unsigned int u32;

#define R_N 1000
#define K_N 80
#define NCOL 81           // K_N + 1 (background col)
#define TOPK_N 100
#define OUT_W 87          // 4 box + 1 score + 1 cls + 81 full scores
#define IMG_W_ 1333.0f
#define IMG_H_ 800.0f
#define CSTR 100          // per-class cand slots (first 100 kept per class provably suffice)
#define NQUAD ((R_N * NCOL) / 4)
#define NMAX 448          // fast-path NMS cap
#define WMAX 7
#define KM (K_N * CSTR)   // 8000 fixed candidate slots
#define POISON 0xAAAAAAAAu  // harness re-poisons d_ws to 0xAA before every launch

__device__ __forceinline__ u32 f32_order(float f) {
    u32 u = __float_as_uint(f);
    return u ^ (((u32)((int)u >> 31)) | 0x80000000u);
}
__device__ __forceinline__ float f32_unorder(u32 o) {
    u32 u = (o & 0x80000000u) ? (o ^ 0x80000000u) : ~o;
    return __uint_as_float(u);
}

// software grid barrier, self-cleaning, load-first CAS (R6-validated pattern:
// plain data stores + __threadfence release + acquire spin is sufficient for
// cross-XCD visibility). 80 blocks co-resident (1 block/CU via LDS).
__device__ __forceinline__ void grid_barrier(u32* bar, u32 nblk) {
    __syncthreads();
    if (threadIdx.x == 0) {
        __threadfence();   // release prior global writes
        if (__hip_atomic_load(bar, __ATOMIC_RELAXED, __HIP_MEMORY_SCOPE_AGENT) == POISON)
            atomicCAS(bar, POISON, 0u);   // exactly one success; value then stays in [0, nblk]
        __hip_atomic_fetch_add(bar, 1u, __ATOMIC_ACQ_REL, __HIP_MEMORY_SCOPE_AGENT);
        while (__hip_atomic_load(bar, __ATOMIC_ACQUIRE, __HIP_MEMORY_SCOPE_AGENT) < nblk)
            __builtin_amdgcn_s_sleep(2);
    }
    __syncthreads();
}

struct P2 {                       // per-class NMS scratch
    float4 bx4[R_N];
    u64 key_s[R_N];
    u64 pool[NMAX * WMAX];        // ukey pre-sort / Mrow bitmatrix / keep[] fallback
    float area[R_N];
    float sc[R_N];                // staged score column (survives both NMS passes)
    u64 keep_words[16];
    int s_n;
};
struct P3 {                       // distributed top-100 scratch (every block)
    u64 keys[KM];                 // all 8000 candidate keys
    int rnk[TOPK_N];              // global ranks of this block's class candidates
};
union SMEM { P2 p2; P3 p3; };

__global__ __launch_bounds__(256, 1) void k_all(const float* __restrict__ boxes,
                                                const float* __restrict__ scores,
                                                float* __restrict__ hdr,
                                                u32* __restrict__ bars,
                                                u64* __restrict__ cand,
                                                float* __restrict__ outp) {
    __shared__ SMEM sm;
    __shared__ float s_sum[4], s_max[4];
    __shared__ int s_cnt[4];
    __shared__ float s_thres;

    const int bid = blockIdx.x, tid = threadIdx.x;
    const int lane = tid & 63, wv = tid >> 6;
    const int c = bid;
    const u64 below = (lane == 0) ? 0ull : (~0ull >> (64 - lane));

    // ---- stage score column c (scattered; overlaps stats below) ----
    for (int r = tid; r < R_N; r += 256) sm.p2.sc[r] = scores[r * NCOL + c];

    // ---- stats partial (sum,max of fg scores over this block's quad slice) ----
    {
        float sum = 0.f, mx = -1e30f;
        int q = bid * 256 + tid;               // 80*256 = 20480 >= 20250 quads
        if (q < NQUAD) {
            float4 v = ((const float4*)scores)[q];
            int m = (q * 4) % NCOL;
            float vv[4] = {v.x, v.y, v.z, v.w};
#pragma unroll
            for (int e = 0; e < 4; ++e) {
                int mm = m + e; if (mm >= NCOL) mm -= NCOL;
                if (mm != K_N) { sum += vv[e]; mx = fmaxf(mx, vv[e]); }
            }
        }
#pragma unroll
        for (int off = 32; off > 0; off >>= 1) {
            sum += __shfl_down(sum, off);
            mx = fmaxf(mx, __shfl_down(mx, off));
        }
        if (lane == 0) { s_sum[wv] = sum; s_max[wv] = mx; }
        __syncthreads();                       // also publishes sc[] for the NMS pass
        if (tid == 0) {
            hdr[2 * bid] = s_sum[0] + s_sum[1] + s_sum[2] + s_sum[3];
            hdr[2 * bid + 1] = fmaxf(fmaxf(s_max[0], s_max[1]), fmaxf(s_max[2], s_max[3]));
        }
    }

    // ---- NMS: speculative pass at th=0.05 (exact in practice), redo if verification fails ----
    float th = 0.05f;
    for (int pass = 0; ; ++pass) {
        // compact valid (sc > th); key = (score desc, orig idx asc) — wave 0 only
        u64* ukey = sm.p2.pool;
        if (wv == 0) {
            int nn = 0;
            for (int r0 = 0; r0 < R_N; r0 += 64) {
                int r = r0 + lane;
                bool pred = (r < R_N) && (sm.p2.sc[r] > th);
                u64 m = __ballot(pred);
                if (pred) {
                    int slot = nn + __popcll(m & below);
                    ukey[slot] = ((u64)f32_order(sm.p2.sc[r]) << 32) | (u64)(u32)(R_N - 1 - r);
                }
                nn += __popcll(m);
            }
            if (lane == 0) sm.p2.s_n = nn;
        }
        __syncthreads();
        const int n = sm.p2.s_n;

        // counting-rank sort + clipped box gather (all 256 threads)
        for (int j = tid; j < n; j += 256) {
            u64 kj = ukey[j];
            int rank = 0;
            for (int k = 0; k < n; ++k) rank += (ukey[k] > kj) ? 1 : 0;
            int r = (R_N - 1) - (int)(kj & 0xFFFFFFFFull);
            float4 b = ((const float4*)boxes)[r * K_N + c];
            float x1 = fminf(fmaxf(b.x, 0.f), IMG_W_);
            float y1 = fminf(fmaxf(b.y, 0.f), IMG_H_);
            float x2 = fminf(fmaxf(b.z, 0.f), IMG_W_);
            float y2 = fminf(fmaxf(b.w, 0.f), IMG_H_);
            sm.p2.key_s[rank] = kj;
            sm.p2.bx4[rank] = make_float4(x1, y1, x2, y2);
            sm.p2.area[rank] = fmaxf(x2 - x1, 0.f) * fmaxf(y2 - y1, 0.f);
        }
        __syncthreads();

        if (n <= NMAX) {
            // suppression bit-matrix (throughput), then register keep-propagation (latency)
            const int W = (n + 63) >> 6;
            u64* Mrow = sm.p2.pool;            // ukey dead after sort
            for (int w = wv; w < W; w += 4) {
                int j = w * 64 + lane;
                bool jv = j < n;
                float4 bj = jv ? sm.p2.bx4[j] : make_float4(0.f, 0.f, 0.f, 0.f);
                float aj = jv ? sm.p2.area[j] : 0.f;
                for (int i = 0; i < n; ++i) {
                    float4 bi = sm.p2.bx4[i];
                    float ai = sm.p2.area[i];
                    float xx1 = fmaxf(bi.x, bj.x), yy1 = fmaxf(bi.y, bj.y);
                    float xx2 = fminf(bi.z, bj.z), yy2 = fminf(bi.w, bj.w);
                    float inter = fmaxf(xx2 - xx1, 0.f) * fmaxf(yy2 - yy1, 0.f);
                    bool sup = jv && (j > i) &&
                               (inter / fmaxf(ai + aj - inter, 1e-9f) > 0.5f);
                    u64 m = __ballot(sup);
                    if (lane == 0) Mrow[i * W + w] = m;
                }
            }
            __syncthreads();

            if (wv == 0) {
                u64 keep_w = 0;
                if (lane < W) {
                    int rem = n - lane * 64;
                    keep_w = (rem >= 64) ? ~0ull : ((1ull << rem) - 1ull);
                }
                const int lw = (lane < W) ? lane : 0;
                u64 fifo[8];
#pragma unroll
                for (int d = 0; d < 8; ++d) fifo[d] = (d < n) ? Mrow[d * W + lw] : 0ull;
                for (int ib = 0; ib < n; ib += 8) {
#pragma unroll
                    for (int d = 0; d < 8; ++d) {
                        int i = ib + d;
                        if (i >= n) break;
                        u64 row = fifo[d];
                        int ip = i + 8;
                        fifo[d] = (ip < n) ? Mrow[ip * W + lw] : 0ull;
                        u64 kw = __shfl(keep_w, i >> 6);
                        if ((kw >> (i & 63)) & 1ull) keep_w &= ~row;
                    }
                }
                if (lane < W) sm.p2.keep_words[lane] = keep_w;
                if (lane >= W && lane < 16) sm.p2.keep_words[lane] = 0;
            }
        } else {
            // fallback: block-wide serial greedy (cold; correctness only)
            int* keep = (int*)sm.p2.pool;
            for (int j = tid; j < n; j += 256) keep[j] = 1;
            __syncthreads();
            for (int i = 0; i < n - 1; ++i) {
                __syncthreads();
                if (!keep[i]) continue;
                float4 bi = sm.p2.bx4[i];
                float ai = sm.p2.area[i];
                for (int j = i + 1 + tid; j < n; j += 256) {
                    if (!keep[j]) continue;
                    float xx1 = fmaxf(bi.x, sm.p2.bx4[j].x), yy1 = fmaxf(bi.y, sm.p2.bx4[j].y);
                    float xx2 = fminf(bi.z, sm.p2.bx4[j].z), yy2 = fminf(bi.w, sm.p2.bx4[j].w);
                    float inter = fmaxf(xx2 - xx1, 0.f) * fmaxf(yy2 - yy1, 0.f);
                    if (inter / fmaxf(ai + sm.p2.area[j] - inter, 1e-9f) > 0.5f) keep[j] = 0;
                }
            }
            __syncthreads();
            if (wv == 0) {
                for (int w = 0; w < 16; ++w) {
                    int j = w * 64 + lane;
                    u64 m = __ballot((j < n) && keep[j]);
                    if (lane == 0) sm.p2.keep_words[w] = m;
                }
            }
        }
        __syncthreads();

        // emit first <=100 kept per class, zero-pad remaining slots (plain stores;
        // visibility across the grid barrier via its release fence + acquire spin)
        if (wv == 0) {
            int kb = 0;
            for (int j0 = 0; j0 < n; j0 += 64) {
                int j = j0 + lane;
                u64 mw = sm.p2.keep_words[j0 >> 6];
                bool kp = (j < n) && ((mw >> lane) & 1ull);
                u64 mm = __ballot(kp);
                int kr = kb + __popcll(mm & below);
                if (kp && kr < CSTR) {
                    u64 kj = sm.p2.key_s[j];
                    u32 osc = (u32)(kj >> 32);
                    int rr = (R_N - 1) - (int)(kj & 0xFFFFFFFFull);
                    int flat = c * R_N + j;
                    cand[c * CSTR + kr] =
                        ((u64)osc << 27) | ((u64)(u32)(131071 - flat) << 10) | (u64)(u32)rr;
                }
                kb += __popcll(mm);
            }
            if (kb > CSTR) kb = CSTR;
            for (int k2 = kb + lane; k2 < CSTR; k2 += 64) cand[c * CSTR + k2] = 0;
        }

        if (pass == 0) {
            grid_barrier(&bars[0], K_N);
            // exact threshold from all 80 partials (wave-parallel, identical per block)
            if (wv == 0) {
                float S = hdr[2 * lane], M = hdr[2 * lane + 1];
                if (lane + 64 < K_N) {
                    S += hdr[2 * (lane + 64)];
                    M = fmaxf(M, hdr[2 * (lane + 64) + 1]);
                }
#pragma unroll
                for (int off = 32; off > 0; off >>= 1) {
                    S += __shfl_down(S, off);
                    M = fmaxf(M, __shfl_down(M, off));
                }
                if (lane == 0)
                    s_thres = fminf(0.05f, 0.5f * (S / (float)(R_N * K_N) + M));
            }
            __syncthreads();
            if (s_thres == 0.05f) break;       // hot path: speculation was exact
            th = s_thres;                      // cold: redo with the true threshold
        } else {
            grid_barrier(&bars[1], K_N);
            break;
        }
    }

    // ---- phase 3 (ALL blocks): stage all keys -> block c ranks its own candidates ----
    {
        // stage 8000 keys (16B vector loads) + count nonzero
        const ulonglong2* cp = (const ulonglong2*)cand;
        int cnt = 0;
        for (int t = tid; t < KM / 2; t += 256) {
            ulonglong2 v = cp[t];
            sm.p3.keys[2 * t] = v.x;
            sm.p3.keys[2 * t + 1] = v.y;
            cnt += (v.x != 0ull) + (v.y != 0ull);
        }
#pragma unroll
        for (int off = 32; off > 0; off >>= 1) cnt += __shfl_down(cnt, off);
        if (lane == 0) s_cnt[wv] = cnt;
        if (tid < TOPK_N) sm.p3.rnk[tid] = 0;
        __syncthreads();
        const int total = s_cnt[0] + s_cnt[1] + s_cnt[2] + s_cnt[3];
        const int target = total < TOPK_N ? total : TOPK_N;

        // 8000 tasks (own-cand i x class-list cc), 8 interleaved binary-search states/thread
        for (int g = 0; g < 4; ++g) {
            int lo[8], hi[8], ii[8], base[8];
            u64 xv[8];
            bool act[8];
#pragma unroll
            for (int s = 0; s < 8; ++s) {
                int t = tid + 256 * (g * 8 + s);
                act[s] = t < KM;
                int i = act[s] ? (t / K_N) : 0;
                int cc = act[s] ? (t - i * K_N) : 0;
                ii[s] = i;
                base[s] = cc * CSTR;
                xv[s] = sm.p3.keys[c * CSTR + i];
                if (xv[s] == 0ull) act[s] = false;
                lo[s] = 0; hi[s] = CSTR;
            }
#pragma unroll
            for (int st = 0; st < 8; ++st) {
#pragma unroll
                for (int s = 0; s < 8; ++s) {
                    int mid = (lo[s] + hi[s]) >> 1;
                    u64 v = sm.p3.keys[base[s] + mid];   // 8 independent LDS reads/step
                    bool live = lo[s] < hi[s];
                    bool gt = live && (v > xv[s]);
                    lo[s] = gt ? mid + 1 : lo[s];
                    hi[s] = (live && !gt) ? mid : hi[s];
                }
            }
#pragma unroll
            for (int s = 0; s < 8; ++s)
                if (act[s] && lo[s] > 0) atomicAdd(&sm.p3.rnk[ii[s]], lo[s]);
        }
        __syncthreads();

        // winners write their full output row (ranks are unique -> race-free)
        if (tid < CSTR) {
            u64 x = sm.p3.keys[c * CSTR + tid];
            int r = sm.p3.rnk[tid];
            if (x != 0ull && r < target) {
                int prop = (int)(x & 0x3FFull);
                float score = f32_unorder((u32)((x >> 27) & 0xFFFFFFFFull));
                int ob = r * OUT_W;
                float4 bx = ((const float4*)boxes)[prop * K_N + c];
                outp[ob + 0] = fminf(fmaxf(bx.x, 0.f), IMG_W_);
                outp[ob + 1] = fminf(fmaxf(bx.y, 0.f), IMG_H_);
                outp[ob + 2] = fminf(fmaxf(bx.z, 0.f), IMG_W_);
                outp[ob + 3] = fminf(fmaxf(bx.w, 0.f), IMG_H_);
                outp[ob + 4] = score;
                outp[ob + 5] = (float)c;
                const int sb = prop * NCOL;
#pragma unroll 9
                for (int j = 0; j < NCOL; ++j) outp[ob + 6 + j] = scores[sb + j];
            }
        }
        // zero tail rows [target, 100), block-strided (disjoint from winner rows)
        for (int row = target + bid; row < TOPK_N; row += K_N) {
            int ob = row * OUT_W;
            for (int e = tid; e < OUT_W; e += 256) outp[ob + e] = 0.f;
        }
    }
}

extern "C" void kernel_launch(void* const* d_in, const int* in_sizes, int n_in,
                              void* d_out, int out_size, void* d_ws, size_t ws_size,
                              hipStream_t stream) {
    const float* boxes = (const float*)d_in[0];
    const float* scores = (const float*)d_in[1];
    float* hdr = (float*)d_ws;                     // 160 f32 partials at [0, 640)
    u32* bars = (u32*)((char*)d_ws + 768);         // 2 self-cleaning barrier counters
    u64* cand = (u64*)((char*)d_ws + 1024);        // 8000 u64 candidate slots

    k_all<<<dim3(K_N), dim3(256), 0, stream>>>(boxes, scores, hdr, bars, cand, (float*)d_out);
}

// Round 10
// 105.906 us; speedup vs baseline: 1.1927x; 1.0516x over previous
//
#include <hip/hip_runtime.h>
#include <stdint.h>

typedef unsigned long long u64;
typedef unsigned int u32;

#define R_N 1000
#define K_N 80
#define NCOL 81           // K_N + 1 (background col)
#define TOPK_N 100
#define OUT_W 87          // 4 box + 1 score + 1 cls + 81 full scores
#define IMG_W_ 1333.0f
#define IMG_H_ 800.0f
#define CSTR 100          // per-class cand slots (first 100 kept per class provably suffice)
#define CSTRP 101         // padded LDS stride: 101%16=5 coprime w/ 16 bank-pairs -> 4-way min
#define NQUAD ((R_N * NCOL) / 4)
#define NMAX 448          // fast-path NMS cap
#define WMAX 7
#define KM (K_N * CSTR)   // 8000 fixed candidate slots
#define POISON 0xAAAAAAAAu  // harness re-poisons d_ws to 0xAA before every launch

__device__ __forceinline__ u32 f32_order(float f) {
    u32 u = __float_as_uint(f);
    return u ^ (((u32)((int)u >> 31)) | 0x80000000u);
}
__device__ __forceinline__ float f32_unorder(u32 o) {
    u32 u = (o & 0x80000000u) ? (o ^ 0x80000000u) : ~o;
    return __uint_as_float(u);
}

// software grid barrier, self-cleaning, load-first CAS (R6/R9-validated).
__device__ __forceinline__ void grid_barrier(u32* bar, u32 nblk) {
    __syncthreads();
    if (threadIdx.x == 0) {
        __threadfence();   // release prior global writes
        if (__hip_atomic_load(bar, __ATOMIC_RELAXED, __HIP_MEMORY_SCOPE_AGENT) == POISON)
            atomicCAS(bar, POISON, 0u);   // exactly one success; value then stays in [0, nblk]
        __hip_atomic_fetch_add(bar, 1u, __ATOMIC_ACQ_REL, __HIP_MEMORY_SCOPE_AGENT);
        while (__hip_atomic_load(bar, __ATOMIC_ACQUIRE, __HIP_MEMORY_SCOPE_AGENT) < nblk)
            __builtin_amdgcn_s_sleep(2);
    }
    __syncthreads();
}

struct P2 {                       // per-class NMS scratch
    float4 bx4[R_N];
    u64 key_s[R_N];
    u64 pool[NMAX * WMAX];        // ukey pre-sort / Mrow bitmatrix / keep[] fallback
    float area[R_N];
    float sc[R_N];                // staged score column (survives both NMS passes)
    u64 keep_words[16];
    int s_n;
};
struct P3 {                       // distributed top-100 scratch (every block)
    u64 keys[K_N * CSTRP];        // all 8000 keys, class stride padded to 101
    int rnk[TOPK_N];
};
union SMEM { P2 p2; P3 p3; };

__global__ __launch_bounds__(256, 1) void k_all(const float* __restrict__ boxes,
                                                const float* __restrict__ scores,
                                                float* __restrict__ hdr,
                                                u32* __restrict__ bars,
                                                u64* __restrict__ cand,
                                                float* __restrict__ outp) {
    __shared__ SMEM sm;
    __shared__ float s_sum[4], s_max[4];
    __shared__ int s_cnt[4];
    __shared__ float s_thres;

    const int bid = blockIdx.x, tid = threadIdx.x;
    const int lane = tid & 63, wv = tid >> 6;
    const int c = bid;
    const u64 below = (lane == 0) ? 0ull : (~0ull >> (64 - lane));

    // ---- stage score column c (scattered; overlaps stats below) ----
    for (int r = tid; r < R_N; r += 256) sm.p2.sc[r] = scores[r * NCOL + c];

    // ---- stats partial (sum,max of fg scores over this block's quad slice) ----
    {
        float sum = 0.f, mx = -1e30f;
        int q = bid * 256 + tid;               // 80*256 = 20480 >= 20250 quads
        if (q < NQUAD) {
            float4 v = ((const float4*)scores)[q];
            int m = (q * 4) % NCOL;
            float vv[4] = {v.x, v.y, v.z, v.w};
#pragma unroll
            for (int e = 0; e < 4; ++e) {
                int mm = m + e; if (mm >= NCOL) mm -= NCOL;
                if (mm != K_N) { sum += vv[e]; mx = fmaxf(mx, vv[e]); }
            }
        }
#pragma unroll
        for (int off = 32; off > 0; off >>= 1) {
            sum += __shfl_down(sum, off);
            mx = fmaxf(mx, __shfl_down(mx, off));
        }
        if (lane == 0) { s_sum[wv] = sum; s_max[wv] = mx; }
        __syncthreads();                       // also publishes sc[] for the NMS pass
        if (tid == 0) {
            hdr[2 * bid] = s_sum[0] + s_sum[1] + s_sum[2] + s_sum[3];
            hdr[2 * bid + 1] = fmaxf(fmaxf(s_max[0], s_max[1]), fmaxf(s_max[2], s_max[3]));
        }
    }

    // ---- NMS: speculative pass at th=0.05 (exact in practice), redo if verification fails ----
    float th = 0.05f;
    for (int pass = 0; ; ++pass) {
        // compact valid (sc > th); key = (score desc, orig idx asc) — wave 0 only
        u64* ukey = sm.p2.pool;
        if (wv == 0) {
            int nn = 0;
            for (int r0 = 0; r0 < R_N; r0 += 64) {
                int r = r0 + lane;
                bool pred = (r < R_N) && (sm.p2.sc[r] > th);
                u64 m = __ballot(pred);
                if (pred) {
                    int slot = nn + __popcll(m & below);
                    ukey[slot] = ((u64)f32_order(sm.p2.sc[r]) << 32) | (u64)(u32)(R_N - 1 - r);
                }
                nn += __popcll(m);
            }
            if (lane == 0) sm.p2.s_n = nn;
        }
        __syncthreads();
        const int n = sm.p2.s_n;

        // counting-rank sort + clipped box gather (all 256 threads)
        for (int j = tid; j < n; j += 256) {
            u64 kj = ukey[j];
            int rank = 0;
            for (int k = 0; k < n; ++k) rank += (ukey[k] > kj) ? 1 : 0;
            int r = (R_N - 1) - (int)(kj & 0xFFFFFFFFull);
            float4 b = ((const float4*)boxes)[r * K_N + c];
            float x1 = fminf(fmaxf(b.x, 0.f), IMG_W_);
            float y1 = fminf(fmaxf(b.y, 0.f), IMG_H_);
            float x2 = fminf(fmaxf(b.z, 0.f), IMG_W_);
            float y2 = fminf(fmaxf(b.w, 0.f), IMG_H_);
            sm.p2.key_s[rank] = kj;
            sm.p2.bx4[rank] = make_float4(x1, y1, x2, y2);
            sm.p2.area[rank] = fmaxf(x2 - x1, 0.f) * fmaxf(y2 - y1, 0.f);
        }
        __syncthreads();

        if (n <= NMAX) {
            // suppression bit-matrix: tasks (w, i-half) spread over all 4 waves
            const int W = (n + 63) >> 6;
            u64* Mrow = sm.p2.pool;            // ukey dead after sort
            const int nh = n >> 1;
            for (int t2 = wv; t2 < 2 * W; t2 += 4) {
                int w = t2 >> 1, ih = t2 & 1;
                int i0 = ih ? nh : 0;
                int i1 = ih ? n : nh;
                int j = w * 64 + lane;
                bool jv = j < n;
                float4 bj = jv ? sm.p2.bx4[j] : make_float4(0.f, 0.f, 0.f, 0.f);
                float aj = jv ? sm.p2.area[j] : 0.f;
                for (int i = i0; i < i1; ++i) {
                    float4 bi = sm.p2.bx4[i];
                    float ai = sm.p2.area[i];
                    float xx1 = fmaxf(bi.x, bj.x), yy1 = fmaxf(bi.y, bj.y);
                    float xx2 = fminf(bi.z, bj.z), yy2 = fminf(bi.w, bj.w);
                    float inter = fmaxf(xx2 - xx1, 0.f) * fmaxf(yy2 - yy1, 0.f);
                    bool sup = jv && (j > i) &&
                               (inter / fmaxf(ai + aj - inter, 1e-9f) > 0.5f);
                    u64 m = __ballot(sup);
                    if (lane == 0) Mrow[i * W + w] = m;
                }
            }
            __syncthreads();

            if (wv == 0) {
                u64 keep_w = 0;
                if (lane < W) {
                    int rem = n - lane * 64;
                    keep_w = (rem >= 64) ? ~0ull : ((1ull << rem) - 1ull);
                }
                const int lw = (lane < W) ? lane : 0;
                u64 fifo[8];
#pragma unroll
                for (int d = 0; d < 8; ++d) fifo[d] = (d < n) ? Mrow[d * W + lw] : 0ull;
                for (int ib = 0; ib < n; ib += 8) {
#pragma unroll
                    for (int d = 0; d < 8; ++d) {
                        int i = ib + d;
                        if (i >= n) break;
                        u64 row = fifo[d];
                        int ip = i + 8;
                        fifo[d] = (ip < n) ? Mrow[ip * W + lw] : 0ull;
                        u64 kw = __shfl(keep_w, i >> 6);
                        if ((kw >> (i & 63)) & 1ull) keep_w &= ~row;
                    }
                }
                if (lane < W) sm.p2.keep_words[lane] = keep_w;
                if (lane >= W && lane < 16) sm.p2.keep_words[lane] = 0;
            }
        } else {
            // fallback: block-wide serial greedy (cold; correctness only)
            int* keep = (int*)sm.p2.pool;
            for (int j = tid; j < n; j += 256) keep[j] = 1;
            __syncthreads();
            for (int i = 0; i < n - 1; ++i) {
                __syncthreads();
                if (!keep[i]) continue;
                float4 bi = sm.p2.bx4[i];
                float ai = sm.p2.area[i];
                for (int j = i + 1 + tid; j < n; j += 256) {
                    if (!keep[j]) continue;
                    float xx1 = fmaxf(bi.x, sm.p2.bx4[j].x), yy1 = fmaxf(bi.y, sm.p2.bx4[j].y);
                    float xx2 = fminf(bi.z, sm.p2.bx4[j].z), yy2 = fminf(bi.w, sm.p2.bx4[j].w);
                    float inter = fmaxf(xx2 - xx1, 0.f) * fmaxf(yy2 - yy1, 0.f);
                    if (inter / fmaxf(ai + sm.p2.area[j] - inter, 1e-9f) > 0.5f) keep[j] = 0;
                }
            }
            __syncthreads();
            if (wv == 0) {
                for (int w = 0; w < 16; ++w) {
                    int j = w * 64 + lane;
                    u64 m = __ballot((j < n) && keep[j]);
                    if (lane == 0) sm.p2.keep_words[w] = m;
                }
            }
        }
        __syncthreads();

        // emit first <=100 kept per class, zero-pad remaining slots
        if (wv == 0) {
            int kb = 0;
            for (int j0 = 0; j0 < n; j0 += 64) {
                int j = j0 + lane;
                u64 mw = sm.p2.keep_words[j0 >> 6];
                bool kp = (j < n) && ((mw >> lane) & 1ull);
                u64 mm = __ballot(kp);
                int kr = kb + __popcll(mm & below);
                if (kp && kr < CSTR) {
                    u64 kj = sm.p2.key_s[j];
                    u32 osc = (u32)(kj >> 32);
                    int rr = (R_N - 1) - (int)(kj & 0xFFFFFFFFull);
                    int flat = c * R_N + j;
                    cand[c * CSTR + kr] =
                        ((u64)osc << 27) | ((u64)(u32)(131071 - flat) << 10) | (u64)(u32)rr;
                }
                kb += __popcll(mm);
            }
            if (kb > CSTR) kb = CSTR;
            for (int k2 = kb + lane; k2 < CSTR; k2 += 64) cand[c * CSTR + k2] = 0;
        }

        if (pass == 0) {
            grid_barrier(&bars[0], K_N);
            // exact threshold from all 80 partials (wave-parallel, identical per block)
            if (wv == 0) {
                float S = hdr[2 * lane], M = hdr[2 * lane + 1];
                if (lane + 64 < K_N) {
                    S += hdr[2 * (lane + 64)];
                    M = fmaxf(M, hdr[2 * (lane + 64) + 1]);
                }
#pragma unroll
                for (int off = 32; off > 0; off >>= 1) {
                    S += __shfl_down(S, off);
                    M = fmaxf(M, __shfl_down(M, off));
                }
                if (lane == 0)
                    s_thres = fminf(0.05f, 0.5f * (S / (float)(R_N * K_N) + M));
            }
            __syncthreads();
            if (s_thres == 0.05f) break;       // hot path: speculation was exact
            th = s_thres;                      // cold: redo with the true threshold
        } else {
            grid_barrier(&bars[1], K_N);
            break;
        }
    }

    // ---- phase 3 (ALL blocks): stage keys (padded stride) -> rank own candidates ----
    {
        // stage 8000 keys into padded layout (pairs never straddle a class: 100 is even)
        const ulonglong2* cp = (const ulonglong2*)cand;
        int cnt = 0;
        for (int t = tid; t < KM / 2; t += 256) {
            ulonglong2 v = cp[t];
            int e0 = 2 * t;
            int cc = e0 / CSTR, pos = e0 - cc * CSTR;
            sm.p3.keys[cc * CSTRP + pos] = v.x;
            sm.p3.keys[cc * CSTRP + pos + 1] = v.y;
            cnt += (v.x != 0ull) + (v.y != 0ull);
        }
#pragma unroll
        for (int off = 32; off > 0; off >>= 1) cnt += __shfl_down(cnt, off);
        if (lane == 0) s_cnt[wv] = cnt;
        if (tid < TOPK_N) sm.p3.rnk[tid] = tid;   // own-class contribution = sorted position
        __syncthreads();
        const int total = s_cnt[0] + s_cnt[1] + s_cnt[2] + s_cnt[3];
        const int target = total < TOPK_N ? total : TOPK_N;

        // 7900 tasks (own-cand i x 79 OTHER class lists), 8 interleaved searches/thread
        for (int g = 0; g < 4; ++g) {
            int lo[8], hi[8], ii[8], base[8];
            u64 xv[8];
            bool act[8];
#pragma unroll
            for (int s = 0; s < 8; ++s) {
                int t = tid + 256 * (g * 8 + s);
                act[s] = t < CSTR * (K_N - 1);
                int i = act[s] ? (t / (K_N - 1)) : 0;
                int cc = act[s] ? (t - i * (K_N - 1)) : 0;
                cc += (cc >= c);               // skip own class
                ii[s] = i;
                base[s] = cc * CSTRP;
                xv[s] = sm.p3.keys[c * CSTRP + i];
                if (xv[s] == 0ull) act[s] = false;
                lo[s] = 0; hi[s] = CSTR;
            }
#pragma unroll
            for (int st = 0; st < 7; ++st) {   // 7 steps close a length-100 interval
#pragma unroll
                for (int s = 0; s < 8; ++s) {
                    int mid = (lo[s] + hi[s]) >> 1;
                    u64 v = sm.p3.keys[base[s] + mid];
                    bool live = lo[s] < hi[s];
                    bool gt = live && (v > xv[s]);
                    lo[s] = gt ? mid + 1 : lo[s];
                    hi[s] = (live && !gt) ? mid : hi[s];
                }
            }
#pragma unroll
            for (int s = 0; s < 8; ++s)
                if (act[s] && lo[s] > 0) atomicAdd(&sm.p3.rnk[ii[s]], lo[s]);
        }
        __syncthreads();

        // winners write their full output row (ranks are unique -> race-free)
        if (tid < CSTR) {
            u64 x = sm.p3.keys[c * CSTRP + tid];
            int r = sm.p3.rnk[tid];
            if (x != 0ull && r < target) {
                int prop = (int)(x & 0x3FFull);
                float score = f32_unorder((u32)((x >> 27) & 0xFFFFFFFFull));
                int ob = r * OUT_W;
                float4 bx = ((const float4*)boxes)[prop * K_N + c];
                outp[ob + 0] = fminf(fmaxf(bx.x, 0.f), IMG_W_);
                outp[ob + 1] = fminf(fmaxf(bx.y, 0.f), IMG_H_);
                outp[ob + 2] = fminf(fmaxf(bx.z, 0.f), IMG_W_);
                outp[ob + 3] = fminf(fmaxf(bx.w, 0.f), IMG_H_);
                outp[ob + 4] = score;
                outp[ob + 5] = (float)c;
                const int sb = prop * NCOL;
#pragma unroll 9
                for (int j = 0; j < NCOL; ++j) outp[ob + 6 + j] = scores[sb + j];
            }
        }
        // zero tail rows [target, 100), block-strided (disjoint from winner rows)
        for (int row = target + bid; row < TOPK_N; row += K_N) {
            int ob = row * OUT_W;
            for (int e = tid; e < OUT_W; e += 256) outp[ob + e] = 0.f;
        }
    }
}

extern "C" void kernel_launch(void* const* d_in, const int* in_sizes, int n_in,
                              void* d_out, int out_size, void* d_ws, size_t ws_size,
                              hipStream_t stream) {
    const float* boxes = (const float*)d_in[0];
    const float* scores = (const float*)d_in[1];
    float* hdr = (float*)d_ws;                     // 160 f32 partials at [0, 640)
    u32* bars = (u32*)((char*)d_ws + 768);         // 2 self-cleaning barrier counters
    u64* cand = (u64*)((char*)d_ws + 1024);        // 8000 u64 candidate slots

    k_all<<<dim3(K_N), dim3(256), 0, stream>>>(boxes, scores, hdr, bars, cand, (float*)d_out);
}